// Round 3
// baseline (380.133 us; speedup 1.0000x reference)
//
#include <hip/hip_runtime.h>
#include <hip/hip_fp16.h>

// Attention: ctx,W = softmax(Q K^T / 32 + mask, padmask) @ V
// B=8, QL=KL=2048, D=1024, fp32 I/O. fp16 MFMA internally (no fp32 MFMA on CDNA4).
#define B_ 8
#define QL_ 2048
#define KL_ 2048
#define D_ 1024

typedef _Float16 f16x8 __attribute__((ext_vector_type(8)));
typedef _Float16 f16x4 __attribute__((ext_vector_type(4)));
typedef float f32x4 __attribute__((ext_vector_type(4)));

// ---------------------------------------------------------------- async 16B
__device__ __forceinline__ void async16(const void* g, void* l) {
  __builtin_amdgcn_global_load_lds(
      (const __attribute__((address_space(1))) unsigned int*)g,
      (__attribute__((address_space(3))) unsigned int*)l, 16, 0, 0);
}

// ---------------------------------------------------------------- fp32->fp16
__global__ __launch_bounds__(256) void cvt_k(const float* __restrict__ X,
                                             _Float16* __restrict__ Xh) {
  const int i = blockIdx.x * 256 + threadIdx.x;  // one thread per 8 floats
  const float4* src = reinterpret_cast<const float4*>(X);
  float4 a = src[i * 2], b = src[i * 2 + 1];
  f16x8 h;
  h[0] = (_Float16)a.x; h[1] = (_Float16)a.y;
  h[2] = (_Float16)a.z; h[3] = (_Float16)a.w;
  h[4] = (_Float16)b.x; h[5] = (_Float16)b.y;
  h[6] = (_Float16)b.z; h[7] = (_Float16)b.w;
  reinterpret_cast<f16x8*>(Xh)[i] = h;
}

// ---------------------------------------------------------------- V transpose
__global__ __launch_bounds__(256) void vt_k(const float* __restrict__ V,
                                            _Float16* __restrict__ VT) {
  __shared__ float tile[32][33];
  const int k0 = blockIdx.x * 32, d0 = blockIdx.y * 32, b = blockIdx.z;
  const float* Vb = V + (size_t)b * KL_ * D_;
  _Float16* VTb = VT + (size_t)b * D_ * KL_;
  const int c = threadIdx.x & 31, r = threadIdx.x >> 5;
#pragma unroll
  for (int s = 0; s < 4; ++s)
    tile[r + s * 8][c] = Vb[(size_t)(k0 + r + s * 8) * D_ + d0 + c];
  __syncthreads();
#pragma unroll
  for (int s = 0; s < 4; ++s)
    VTb[(size_t)(d0 + r + s * 8) * KL_ + k0 + c] = (_Float16)tile[c][r + s * 8];
}

// ============================================================ 256^2 8-phase GEMM
// BM=BN=256, BK=64, 512 thr = 8 waves (2M x 4N), per-wave 128x64 out,
// acc[8][4] f32x4. LDS 128 KiB: 2 bufs x (A 256x64 + B 256x64) fp16.
// Per K-tile: 4 phases (MFMA quadrants of 16), stage issues front-loaded in
// phase 1 (next tile -> other buffer), single vmcnt(0) drain at boundary
// (loads are ~4 phases old -> latency covered). 8-chunk XOR swizzle
// (chunk ^ row&7) -> conflict-free ds_read_b128; global source pre-swizzled
// so global_load_lds dest stays lane-linear (m104/m173).
// SCORES=true : C = (QK^T)/32 + mask, pad -> -1e12  (Nc=2048, Kc=1024)
// SCORES=false: C = W @ VT^T                        (Nc=1024, Kc=2048)
template <bool SCORES>
__global__ __launch_bounds__(512, 2) void fgemm256_k(
    const _Float16* __restrict__ Ah, const _Float16* __restrict__ Bh,
    float* __restrict__ Cg, const float* __restrict__ mask,
    const int* __restrict__ pad) {
  constexpr int Mc = 2048;
  constexpr int Nc = SCORES ? 2048 : 1024;
  constexpr int Kc = SCORES ? 1024 : 2048;
  constexpr int NIT = Kc / 64;
  constexpr int GY = Nc / 256;            // n-tiles
  constexpr int CHUNK = (Mc / 256) * GY;  // blocks per batch (= per XCD chunk)

  extern __shared__ char lds[];  // 131072 B

  const int t = threadIdx.x;
  const int lane = t & 63;
  const int wid = t >> 6;              // 0..7
  const int wr = wid >> 2, wc = wid & 3;
  const int lo = lane & 15, hi = lane >> 4;

  // XCD-chunked swizzle: each XCD gets one batch's blocks (bijective: 8|nwg).
  const int orig = blockIdx.x;
  const int wgid = (orig & 7) * CHUNK + (orig >> 3);
  const int b = wgid / CHUNK;
  const int rem = wgid % CHUNK;
  const int m0 = (rem / GY) * 256;
  const int n0 = (rem % GY) * 256;

  const _Float16* Ab = Ah + (size_t)b * Mc * Kc;
  const _Float16* Bb = Bh + (size_t)b * Nc * Kc;

  // ---- staging geometry (lane-linear LDS dest, pre-swizzled global source)
  const int rowbase = wid * 8 + (lane >> 3);            // 0..63
  const int gch = (lane & 7) ^ ((lane >> 3) & 7);       // source 16B chunk
  size_t aoff[2][2], boff[2][2];                        // [half][s]
#pragma unroll
  for (int h = 0; h < 2; ++h)
#pragma unroll
    for (int s = 0; s < 2; ++s) {
      aoff[h][s] = (size_t)(m0 + h * 128 + s * 64 + rowbase) * Kc + gch * 8;
      boff[h][s] = (size_t)(n0 + h * 128 + s * 64 + rowbase) * Kc + gch * 8;
    }

  auto stage = [&](int kt, int buf) {
    char* Ad = lds + buf * 65536;
    char* Bd = Ad + 32768;
    const int kb = kt * 64;
#pragma unroll
    for (int h = 0; h < 2; ++h)
#pragma unroll
      for (int s = 0; s < 2; ++s) {
        const int ldst = h * 16384 + s * 8192 + wid * 1024;  // wave-uniform
        async16(Ab + aoff[h][s] + kb, Ad + ldst);
        async16(Bb + boff[h][s] + kb, Bd + ldst);
      }
  };

  // ---- fragment read offsets (byte, within operand buffer)
  int vA[2], vB[2];
#pragma unroll
  for (int ks = 0; ks < 2; ++ks) {
    const int swz = (((ks << 2) | hi) ^ (lo & 7)) << 4;
    vA[ks] = wr * 16384 + lo * 128 + swz;
    vB[ks] = (wc >> 1) * 16384 + ((wc & 1) * 64 + lo) * 128 + swz;
  }

  f32x4 acc[8][4];
#pragma unroll
  for (int m = 0; m < 8; ++m)
#pragma unroll
    for (int n = 0; n < 4; ++n)
#pragma unroll
      for (int i = 0; i < 4; ++i) acc[m][n][i] = 0.0f;

  f16x8 aF[4][2];        // current m-quadrant: [m][ks]
  f16x8 bF[2][2][2];     // both n-quadrants:  [nq][n][ks]

  // prologue: tile 0 -> buf 0
  stage(0, 0);
  asm volatile("s_waitcnt vmcnt(0)" ::: "memory");
  __builtin_amdgcn_s_barrier();
  __builtin_amdgcn_sched_barrier(0);

  for (int kt = 0; kt < NIT; ++kt) {
    const int cur = kt & 1;
    const char* Ac = lds + cur * 65536;
    const char* Bc = Ac + 32768;

    // ---- phase 1: read A(mq=0) + B(nq=0); issue next tile's 8 stages
#pragma unroll
    for (int m = 0; m < 4; ++m)
#pragma unroll
      for (int ks = 0; ks < 2; ++ks)
        aF[m][ks] = *reinterpret_cast<const f16x8*>(Ac + vA[ks] + m * 2048);
#pragma unroll
    for (int n = 0; n < 2; ++n)
#pragma unroll
      for (int ks = 0; ks < 2; ++ks)
        bF[0][n][ks] = *reinterpret_cast<const f16x8*>(Bc + vB[ks] + n * 2048);
    if (kt + 1 < NIT) stage(kt + 1, cur ^ 1);
    __builtin_amdgcn_s_barrier();
    __builtin_amdgcn_sched_barrier(0);
    __builtin_amdgcn_s_setprio(1);
#pragma unroll
    for (int ks = 0; ks < 2; ++ks)
#pragma unroll
      for (int m = 0; m < 4; ++m)
#pragma unroll
        for (int n = 0; n < 2; ++n)
          acc[m][n] = __builtin_amdgcn_mfma_f32_16x16x32_f16(
              aF[m][ks], bF[0][n][ks], acc[m][n], 0, 0, 0);
    __builtin_amdgcn_s_setprio(0);
    __builtin_amdgcn_s_barrier();
    __builtin_amdgcn_sched_barrier(0);

    // ---- phase 2: read B(nq=1); MFMA quad(0,1)
#pragma unroll
    for (int n = 0; n < 2; ++n)
#pragma unroll
      for (int ks = 0; ks < 2; ++ks)
        bF[1][n][ks] =
            *reinterpret_cast<const f16x8*>(Bc + vB[ks] + (2 + n) * 2048);
    __builtin_amdgcn_s_barrier();
    __builtin_amdgcn_sched_barrier(0);
    __builtin_amdgcn_s_setprio(1);
#pragma unroll
    for (int ks = 0; ks < 2; ++ks)
#pragma unroll
      for (int m = 0; m < 4; ++m)
#pragma unroll
        for (int n = 0; n < 2; ++n)
          acc[m][2 + n] = __builtin_amdgcn_mfma_f32_16x16x32_f16(
              aF[m][ks], bF[1][n][ks], acc[m][2 + n], 0, 0, 0);
    __builtin_amdgcn_s_setprio(0);
    __builtin_amdgcn_s_barrier();
    __builtin_amdgcn_sched_barrier(0);

    // ---- phase 3: read A(mq=1); MFMA quad(1,1)
#pragma unroll
    for (int m = 0; m < 4; ++m)
#pragma unroll
      for (int ks = 0; ks < 2; ++ks)
        aF[m][ks] =
            *reinterpret_cast<const f16x8*>(Ac + vA[ks] + (4 + m) * 2048);
    __builtin_amdgcn_s_barrier();
    __builtin_amdgcn_sched_barrier(0);
    __builtin_amdgcn_s_setprio(1);
#pragma unroll
    for (int ks = 0; ks < 2; ++ks)
#pragma unroll
      for (int m = 0; m < 4; ++m)
#pragma unroll
        for (int n = 0; n < 2; ++n)
          acc[4 + m][2 + n] = __builtin_amdgcn_mfma_f32_16x16x32_f16(
              aF[m][ks], bF[1][n][ks], acc[4 + m][2 + n], 0, 0, 0);
    __builtin_amdgcn_s_setprio(0);
    __builtin_amdgcn_s_barrier();
    __builtin_amdgcn_sched_barrier(0);

    // ---- phase 4: MFMA quad(1,0); boundary drain (loads are ~4 phases old)
    __builtin_amdgcn_s_setprio(1);
#pragma unroll
    for (int ks = 0; ks < 2; ++ks)
#pragma unroll
      for (int m = 0; m < 4; ++m)
#pragma unroll
        for (int n = 0; n < 2; ++n)
          acc[4 + m][n] = __builtin_amdgcn_mfma_f32_16x16x32_f16(
              aF[m][ks], bF[0][n][ks], acc[4 + m][n], 0, 0, 0);
    __builtin_amdgcn_s_setprio(0);
    asm volatile("s_waitcnt vmcnt(0)" ::: "memory");  // own stages landed
    __builtin_amdgcn_s_barrier();                     // all waves' landed
    __builtin_amdgcn_sched_barrier(0);
  }

  // ---- epilogue. C layout (verified): col = lane&15, row = (lane>>4)*4 + i.
  float* Cb = Cg + (size_t)b * Mc * Nc;
  if constexpr (SCORES) {
    const float inv_t = 0.03125f;  // 1/sqrt(1024)
#pragma unroll
    for (int n = 0; n < 4; ++n) {
      const int col = n0 + wc * 64 + n * 16 + lo;
      const int pd = pad[b * Nc + col];
#pragma unroll
      for (int m = 0; m < 8; ++m) {
        const int r0 = m0 + wr * 128 + m * 16 + hi * 4;
#pragma unroll
        for (int i = 0; i < 4; ++i) {
          float s = acc[m][n][i] * inv_t + mask[(size_t)(r0 + i) * Nc + col];
          if (pd) s = -1e12f;  // masked_fill AFTER mask-add (replace)
          Cb[(size_t)(r0 + i) * Nc + col] = s;
        }
      }
    }
  } else {
#pragma unroll
    for (int n = 0; n < 4; ++n) {
      const int col = n0 + wc * 64 + n * 16 + lo;
#pragma unroll
      for (int m = 0; m < 8; ++m) {
        const int r0 = m0 + wr * 128 + m * 16 + hi * 4;
#pragma unroll
        for (int i = 0; i < 4; ++i)
          Cb[(size_t)(r0 + i) * Nc + col] = acc[m][n][i];
      }
    }
  }
}

// ------------------------------------------------- fallback GEMM (round-1)
__device__ __forceinline__ int lds_off(int row, int slot) {
  return (row << 6) + (((slot << 4) ^ ((row & 3) << 4)));
}

template <bool SCORES>
__global__ __launch_bounds__(256) void gemm_k(
    const float* __restrict__ Ag, const float* __restrict__ Bf,
    const _Float16* __restrict__ Bh, float* __restrict__ Cg,
    const float* __restrict__ mask, const int* __restrict__ pad) {
  constexpr int Mc = 2048;
  constexpr int Nc = SCORES ? 2048 : 1024;
  constexpr int Kc = SCORES ? 1024 : 2048;
  constexpr int NIT = Kc / 32;

  __shared__ alignas(16) char smem[32768];

  const int t = threadIdx.x;
  const int lane = t & 63;
  const int wid = t >> 6;
  const int wr = wid >> 1, wc = wid & 1;
  const int lo = lane & 15, hi = lane >> 4;
  const int q0 = blockIdx.x * 128, n0 = blockIdx.y * 128;
  const int b = blockIdx.z;

  const float* Ab = Ag + (size_t)b * Mc * Kc;
  const float* Bfb = Bf ? (Bf + (size_t)b * Nc * Kc) : Bf;
  const _Float16* Bhb = Bh ? (Bh + (size_t)b * Nc * Kc) : Bh;

  const int srow = t >> 2;
  const int sc8 = t & 3;

  float4 ra[4];
  float4 rbf[4];
  f16x8 rbh[2];

  auto gload = [&](int kb) {
#pragma unroll
    for (int s = 0; s < 2; ++s) {
      const int row = srow + s * 64;
      const float4* ga = reinterpret_cast<const float4*>(
          Ab + (size_t)(q0 + row) * Kc + kb + sc8 * 8);
      ra[s * 2] = ga[0];
      ra[s * 2 + 1] = ga[1];
      if constexpr (SCORES) {
        const float4* gb = reinterpret_cast<const float4*>(
            Bfb + (size_t)(n0 + row) * Kc + kb + sc8 * 8);
        rbf[s * 2] = gb[0];
        rbf[s * 2 + 1] = gb[1];
      } else {
        rbh[s] = *reinterpret_cast<const f16x8*>(
            Bhb + (size_t)(n0 + row) * Kc + kb + sc8 * 8);
      }
    }
  };

  auto sstore = [&](int buf) {
    char* Ad = smem + buf * 8192;
    char* Bd = smem + 16384 + buf * 8192;
#pragma unroll
    for (int s = 0; s < 2; ++s) {
      const int row = srow + s * 64;
      f16x8 ha;
      ha[0] = (_Float16)ra[s * 2].x;
      ha[1] = (_Float16)ra[s * 2].y;
      ha[2] = (_Float16)ra[s * 2].z;
      ha[3] = (_Float16)ra[s * 2].w;
      ha[4] = (_Float16)ra[s * 2 + 1].x;
      ha[5] = (_Float16)ra[s * 2 + 1].y;
      ha[6] = (_Float16)ra[s * 2 + 1].z;
      ha[7] = (_Float16)ra[s * 2 + 1].w;
      *reinterpret_cast<f16x8*>(Ad + lds_off(row, sc8)) = ha;
      if constexpr (SCORES) {
        f16x8 hb;
        hb[0] = (_Float16)rbf[s * 2].x;
        hb[1] = (_Float16)rbf[s * 2].y;
        hb[2] = (_Float16)rbf[s * 2].z;
        hb[3] = (_Float16)rbf[s * 2].w;
        hb[4] = (_Float16)rbf[s * 2 + 1].x;
        hb[5] = (_Float16)rbf[s * 2 + 1].y;
        hb[6] = (_Float16)rbf[s * 2 + 1].z;
        hb[7] = (_Float16)rbf[s * 2 + 1].w;
        *reinterpret_cast<f16x8*>(Bd + lds_off(row, sc8)) = hb;
      } else {
        *reinterpret_cast<f16x8*>(Bd + lds_off(row, sc8)) = rbh[s];
      }
    }
  };

  f32x4 acc[4][4];
#pragma unroll
  for (int m = 0; m < 4; ++m)
#pragma unroll
    for (int n = 0; n < 4; ++n)
#pragma unroll
      for (int i = 0; i < 4; ++i) acc[m][n][i] = 0.0f;

  gload(0);
  sstore(0);
  __syncthreads();

  for (int it = 0; it < NIT; ++it) {
    const int cur = it & 1;
    if (it + 1 < NIT) gload((it + 1) * 32);
    const char* Ad = smem + cur * 8192;
    const char* Bd = smem + 16384 + cur * 8192;
    f16x8 af[4], bfr[4];
#pragma unroll
    for (int m = 0; m < 4; ++m)
      af[m] = *reinterpret_cast<const f16x8*>(
          Ad + lds_off(wr * 64 + m * 16 + lo, hi));
#pragma unroll
    for (int n = 0; n < 4; ++n)
      bfr[n] = *reinterpret_cast<const f16x8*>(
          Bd + lds_off(wc * 64 + n * 16 + lo, hi));
#pragma unroll
    for (int m = 0; m < 4; ++m)
#pragma unroll
      for (int n = 0; n < 4; ++n)
        acc[m][n] = __builtin_amdgcn_mfma_f32_16x16x32_f16(af[m], bfr[n],
                                                           acc[m][n], 0, 0, 0);
    if (it + 1 < NIT) sstore(cur ^ 1);
    __syncthreads();
  }

  float* Cb = Cg + (size_t)b * Mc * Nc;
  if constexpr (SCORES) {
    const float inv_t = 0.03125f;
#pragma unroll
    for (int n = 0; n < 4; ++n) {
      const int col = n0 + wc * 64 + n * 16 + lo;
      const int pd = pad[b * Nc + col];
#pragma unroll
      for (int m = 0; m < 4; ++m) {
        const int r0 = q0 + wr * 64 + m * 16 + hi * 4;
#pragma unroll
        for (int i = 0; i < 4; ++i) {
          float s = acc[m][n][i] * inv_t + mask[(size_t)(r0 + i) * Nc + col];
          if (pd) s = -1e12f;
          Cb[(size_t)(r0 + i) * Nc + col] = s;
        }
      }
    }
  } else {
#pragma unroll
    for (int n = 0; n < 4; ++n) {
      const int col = n0 + wc * 64 + n * 16 + lo;
#pragma unroll
      for (int m = 0; m < 4; ++m) {
        const int r0 = q0 + wr * 64 + m * 16 + hi * 4;
#pragma unroll
        for (int i = 0; i < 4; ++i)
          Cb[(size_t)(r0 + i) * Nc + col] = acc[m][n][i];
      }
    }
  }
}

// ---------------------------------------------------------------- row softmax
__global__ __launch_bounds__(256) void softmax_k(float* __restrict__ W,
                                                 _Float16* __restrict__ Wh) {
  const int row = blockIdx.x * 4 + (threadIdx.x >> 6);
  const int lane = threadIdx.x & 63;
  float4* Wr = reinterpret_cast<float4*>(W + (size_t)row * KL_);
  float4 v[8];
#pragma unroll
  for (int s = 0; s < 8; ++s) v[s] = Wr[s * 64 + lane];
  float mx = -3.402823466e38f;
#pragma unroll
  for (int s = 0; s < 8; ++s)
    mx = fmaxf(mx, fmaxf(fmaxf(v[s].x, v[s].y), fmaxf(v[s].z, v[s].w)));
#pragma unroll
  for (int off = 32; off > 0; off >>= 1) mx = fmaxf(mx, __shfl_xor(mx, off));
  float sum = 0.0f;
#pragma unroll
  for (int s = 0; s < 8; ++s) {
    v[s].x = __expf(v[s].x - mx);
    v[s].y = __expf(v[s].y - mx);
    v[s].z = __expf(v[s].z - mx);
    v[s].w = __expf(v[s].w - mx);
    sum += v[s].x + v[s].y + v[s].z + v[s].w;
  }
#pragma unroll
  for (int off = 32; off > 0; off >>= 1) sum += __shfl_xor(sum, off);
  const float inv = 1.0f / sum;
  f16x4* Whr = Wh ? reinterpret_cast<f16x4*>(Wh + (size_t)row * KL_) : nullptr;
#pragma unroll
  for (int s = 0; s < 8; ++s) {
    float4 o;
    o.x = v[s].x * inv;
    o.y = v[s].y * inv;
    o.z = v[s].z * inv;
    o.w = v[s].w * inv;
    Wr[s * 64 + lane] = o;
    if (Whr) {
      f16x4 h;
      h[0] = (_Float16)o.x;
      h[1] = (_Float16)o.y;
      h[2] = (_Float16)o.z;
      h[3] = (_Float16)o.w;
      Whr[s * 64 + lane] = h;
    }
  }
}

// ---------------------------------------------------------------- launch
extern "C" void kernel_launch(void* const* d_in, const int* in_sizes, int n_in,
                              void* d_out, int out_size, void* d_ws,
                              size_t ws_size, hipStream_t stream) {
  const float* Q = (const float*)d_in[0];
  const float* K = (const float*)d_in[1];
  const float* V = (const float*)d_in[2];
  const float* mask = (const float*)d_in[3];
  const int* pad = (const int*)d_in[4];

  float* ctx = (float*)d_out;              // [8][2048][1024]
  float* W = ctx + (size_t)B_ * QL_ * D_;  // [8][2048][2048]

  const size_t MB = 1024 * 1024;
  _Float16* VT = (_Float16*)d_ws;  // [8][1024][2048] fp16 = 32 MiB

  if (ws_size >= 96 * MB) {
    _Float16* Qh = (_Float16*)((char*)d_ws + 32 * MB);  // 32 MiB
    _Float16* Kh = (_Float16*)((char*)d_ws + 64 * MB);  // 32 MiB
    _Float16* Wh = Qh;                                  // 64 MiB, after reuse

    // opt-in to 128 KiB dynamic LDS (idempotent, non-stream API)
    (void)hipFuncSetAttribute((const void*)fgemm256_k<true>,
                              hipFuncAttributeMaxDynamicSharedMemorySize,
                              131072);
    (void)hipFuncSetAttribute((const void*)fgemm256_k<false>,
                              hipFuncAttributeMaxDynamicSharedMemorySize,
                              131072);

    cvt_k<<<dim3(B_ * QL_ * D_ / 8 / 256), 256, 0, stream>>>(Q, Qh);
    cvt_k<<<dim3(B_ * KL_ * D_ / 8 / 256), 256, 0, stream>>>(K, Kh);
    vt_k<<<dim3(KL_ / 32, D_ / 32, B_), 256, 0, stream>>>(V, VT);
    fgemm256_k<true><<<dim3(B_ * (QL_ / 256) * (KL_ / 256)), 512, 131072,
                       stream>>>(Qh, Kh, W, mask, pad);
    softmax_k<<<dim3(B_ * QL_ / 4), 256, 0, stream>>>(W, Wh);
    fgemm256_k<false><<<dim3(B_ * (QL_ / 256) * (D_ / 256)), 512, 131072,
                        stream>>>(Wh, VT, ctx, nullptr, nullptr);
  } else {
    vt_k<<<dim3(KL_ / 32, D_ / 32, B_), 256, 0, stream>>>(V, VT);
    gemm_k<true><<<dim3(QL_ / 128, KL_ / 128, B_), 256, 0, stream>>>(
        Q, K, nullptr, W, mask, pad);
    softmax_k<<<dim3(B_ * QL_ / 4), 256, 0, stream>>>(W, nullptr);
    gemm_k<false><<<dim3(QL_ / 128, D_ / 128, B_), 256, 0, stream>>>(
        W, nullptr, VT, ctx, nullptr, nullptr);
  }
}

// Round 4
// 370.381 us; speedup vs baseline: 1.0263x; 1.0263x over previous
//
#include <hip/hip_runtime.h>
#include <hip/hip_fp16.h>

// Attention: ctx,W = softmax(Q K^T / 32 + mask, padmask) @ V
// B=8, QL=KL=2048, D=1024, fp32 I/O. fp16 MFMA internally (no fp32 MFMA on CDNA4).
#define B_ 8
#define QL_ 2048
#define KL_ 2048
#define D_ 1024

typedef _Float16 f16x8 __attribute__((ext_vector_type(8)));
typedef _Float16 f16x4 __attribute__((ext_vector_type(4)));
typedef float f32x4 __attribute__((ext_vector_type(4)));

// ---------------------------------------------------------------- async 16B
__device__ __forceinline__ void async16(const void* g, void* l) {
  __builtin_amdgcn_global_load_lds(
      (const __attribute__((address_space(1))) unsigned int*)g,
      (__attribute__((address_space(3))) unsigned int*)l, 16, 0, 0);
}

// ---------------------------------------------------------------- fp32->fp16
__global__ __launch_bounds__(256) void cvt_k(const float* __restrict__ X,
                                             _Float16* __restrict__ Xh) {
  const int i = blockIdx.x * 256 + threadIdx.x;  // one thread per 8 floats
  const float4* src = reinterpret_cast<const float4*>(X);
  float4 a = src[i * 2], b = src[i * 2 + 1];
  f16x8 h;
  h[0] = (_Float16)a.x; h[1] = (_Float16)a.y;
  h[2] = (_Float16)a.z; h[3] = (_Float16)a.w;
  h[4] = (_Float16)b.x; h[5] = (_Float16)b.y;
  h[6] = (_Float16)b.z; h[7] = (_Float16)b.w;
  reinterpret_cast<f16x8*>(Xh)[i] = h;
}

// ---------------------------------------------------------------- V transpose
__global__ __launch_bounds__(256) void vt_k(const float* __restrict__ V,
                                            _Float16* __restrict__ VT) {
  __shared__ float tile[32][33];
  const int k0 = blockIdx.x * 32, d0 = blockIdx.y * 32, b = blockIdx.z;
  const float* Vb = V + (size_t)b * KL_ * D_;
  _Float16* VTb = VT + (size_t)b * D_ * KL_;
  const int c = threadIdx.x & 31, r = threadIdx.x >> 5;
#pragma unroll
  for (int s = 0; s < 4; ++s)
    tile[r + s * 8][c] = Vb[(size_t)(k0 + r + s * 8) * D_ + d0 + c];
  __syncthreads();
#pragma unroll
  for (int s = 0; s < 4; ++s)
    VTb[(size_t)(d0 + r + s * 8) * KL_ + k0 + c] = (_Float16)tile[c][r + s * 8];
}

// ---------------------------------------------------------------- fast GEMM
// Round-2 verified structure (128x128 tile, BK=32, 4 waves 2x2, 64x64/wave,
// 4x4 MFMA 16x16x32_f16, global_load_lds(16B) with pre-swizzled source,
// 0 measured bank conflicts) + T3-minimum 2-phase pipeline:
//   stage(0); sync;
//   for t: { stage(t+1 -> other buf);  ds_read+MFMA on cur buf;  sync; }
// The stage ISSUE precedes compute, so tile t+1's HBM latency hides under
// tile t's MFMA cluster; __syncthreads supplies the vmcnt(0)+barrier drain.
// LDS 32 KiB (2 bufs x (A 8K + B 8K)) keeps ~4 blocks/CU of TLP.
// SCORES=true : C[b][q][k] = (QK^T)/32 + mask, pad -> -1e12   (Kc=1024)
// SCORES=false: C[b][q][d] = W @ VT^T                          (Kc=2048)
template <bool SCORES>
__global__ __launch_bounds__(256) void fgemm_k(
    const _Float16* __restrict__ Ah, const _Float16* __restrict__ Bh,
    float* __restrict__ Cg, const float* __restrict__ mask,
    const int* __restrict__ pad) {
  constexpr int Mc = 2048;
  constexpr int Nc = SCORES ? 2048 : 1024;
  constexpr int Kc = SCORES ? 1024 : 2048;
  constexpr int NIT = Kc / 32;

  __shared__ alignas(16) _Float16 As[2][128 * 32];
  __shared__ alignas(16) _Float16 Bs[2][128 * 32];

  const int t = threadIdx.x;
  const int lane = t & 63;
  const int wid = t >> 6;
  const int wr = wid >> 1, wc = wid & 1;
  const int lo = lane & 15, hi = lane >> 4;
  const int m0 = blockIdx.x * 128, n0 = blockIdx.y * 128;
  const int b = blockIdx.z;

  const _Float16* Ab = Ah + (size_t)b * Mc * Kc;
  const _Float16* Bb = Bh + (size_t)b * Nc * Kc;

  const int srow = t >> 2;   // staging row within a 64-row sweep
  const int dslot = t & 3;   // lane-linear LDS 16B slot within the row

  auto stage = [&](int it, int buf) {
    const int kb = it * 32;
#pragma unroll
    for (int s = 0; s < 2; ++s) {
      const int row = s * 64 + srow;
      const int gs = dslot ^ ((row >> 1) & 3);  // pre-swizzled source chunk
      async16(Ab + (size_t)(m0 + row) * Kc + kb + gs * 8,
              &As[buf][s * 2048 + wid * 512]);  // wave-uniform base + lane*16
      async16(Bb + (size_t)(n0 + row) * Kc + kb + gs * 8,
              &Bs[buf][s * 2048 + wid * 512]);
    }
  };

  f32x4 acc[4][4];
#pragma unroll
  for (int m = 0; m < 4; ++m)
#pragma unroll
    for (int n = 0; n < 4; ++n)
#pragma unroll
      for (int i = 0; i < 4; ++i) acc[m][n][i] = 0.0f;

  stage(0, 0);
  __syncthreads();  // vmcnt(0) drain + barrier (HIP __syncthreads semantics)

  for (int it = 0; it < NIT; ++it) {
    const int cur = it & 1;
    if (it + 1 < NIT) stage(it + 1, cur ^ 1);  // issue-first prefetch
    __builtin_amdgcn_sched_barrier(0);         // keep issues above compute
    f16x8 af[4], bfr[4];
#pragma unroll
    for (int m = 0; m < 4; ++m) {
      const int r = wr * 64 + m * 16 + lo;
      const int sl = hi ^ ((r >> 1) & 3);
      af[m] = *reinterpret_cast<const f16x8*>(&As[cur][r * 32 + sl * 8]);
    }
#pragma unroll
    for (int n = 0; n < 4; ++n) {
      const int r = wc * 64 + n * 16 + lo;
      const int sl = hi ^ ((r >> 1) & 3);
      bfr[n] = *reinterpret_cast<const f16x8*>(&Bs[cur][r * 32 + sl * 8]);
    }
#pragma unroll
    for (int m = 0; m < 4; ++m)
#pragma unroll
      for (int n = 0; n < 4; ++n)
        acc[m][n] = __builtin_amdgcn_mfma_f32_16x16x32_f16(af[m], bfr[n],
                                                           acc[m][n], 0, 0, 0);
    __syncthreads();  // drains vmcnt(0): next buffer landed; cur reads done
  }

  // Epilogue. C layout (verified): col = lane&15, row = (lane>>4)*4 + i.
  float* Cb = Cg + (size_t)b * Mc * Nc;
  if constexpr (SCORES) {
    const float inv_t = 0.03125f;  // 1/sqrt(1024)
#pragma unroll
    for (int n = 0; n < 4; ++n) {
      const int col = n0 + wc * 64 + n * 16 + lo;
      const int pd = pad[b * Nc + col];
#pragma unroll
      for (int m = 0; m < 4; ++m) {
        const int r0 = m0 + wr * 64 + m * 16 + hi * 4;
#pragma unroll
        for (int i = 0; i < 4; ++i) {
          float s = acc[m][n][i] * inv_t + mask[(size_t)(r0 + i) * Nc + col];
          if (pd) s = -1e12f;  // masked_fill AFTER mask-add (replace, not add)
          Cb[(size_t)(r0 + i) * Nc + col] = s;
        }
      }
    }
  } else {
#pragma unroll
    for (int n = 0; n < 4; ++n) {
      const int col = n0 + wc * 64 + n * 16 + lo;
#pragma unroll
      for (int m = 0; m < 4; ++m) {
        const int r0 = m0 + wr * 64 + m * 16 + hi * 4;
#pragma unroll
        for (int i = 0; i < 4; ++i)
          Cb[(size_t)(r0 + i) * Nc + col] = acc[m][n][i];
      }
    }
  }
}

// ---------------------------------------------------------------- row softmax
// One wave per row of 2048 fp32 (32 VGPR), exact max/sum, in-place normalize.
// Masked entries are -1e12 -> exp underflows to exactly 0 (matches jax).
// All-masked row degenerates to uniform 1/2048 (also matches jax).
// Also emits a fp16 copy (PV's A operand).
__global__ __launch_bounds__(256) void softmax_k(float* __restrict__ W,
                                                 _Float16* __restrict__ Wh) {
  const int row = blockIdx.x * 4 + (threadIdx.x >> 6);
  const int lane = threadIdx.x & 63;
  float4* Wr = reinterpret_cast<float4*>(W + (size_t)row * KL_);
  float4 v[8];
#pragma unroll
  for (int s = 0; s < 8; ++s) v[s] = Wr[s * 64 + lane];
  float mx = -3.402823466e38f;
#pragma unroll
  for (int s = 0; s < 8; ++s)
    mx = fmaxf(mx, fmaxf(fmaxf(v[s].x, v[s].y), fmaxf(v[s].z, v[s].w)));
#pragma unroll
  for (int off = 32; off > 0; off >>= 1) mx = fmaxf(mx, __shfl_xor(mx, off));
  float sum = 0.0f;
#pragma unroll
  for (int s = 0; s < 8; ++s) {
    v[s].x = __expf(v[s].x - mx);
    v[s].y = __expf(v[s].y - mx);
    v[s].z = __expf(v[s].z - mx);
    v[s].w = __expf(v[s].w - mx);
    sum += v[s].x + v[s].y + v[s].z + v[s].w;
  }
#pragma unroll
  for (int off = 32; off > 0; off >>= 1) sum += __shfl_xor(sum, off);
  const float inv = 1.0f / sum;
  f16x4* Whr = reinterpret_cast<f16x4*>(Wh + (size_t)row * KL_);
#pragma unroll
  for (int s = 0; s < 8; ++s) {
    float4 o;
    o.x = v[s].x * inv;
    o.y = v[s].y * inv;
    o.z = v[s].z * inv;
    o.w = v[s].w * inv;
    Wr[s * 64 + lane] = o;
    f16x4 h;
    h[0] = (_Float16)o.x;
    h[1] = (_Float16)o.y;
    h[2] = (_Float16)o.z;
    h[3] = (_Float16)o.w;
    Whr[s * 64 + lane] = h;
  }
}

// ---------------------------------------------------------------- launch
extern "C" void kernel_launch(void* const* d_in, const int* in_sizes, int n_in,
                              void* d_out, int out_size, void* d_ws,
                              size_t ws_size, hipStream_t stream) {
  const float* Q = (const float*)d_in[0];
  const float* K = (const float*)d_in[1];
  const float* V = (const float*)d_in[2];
  const float* mask = (const float*)d_in[3];
  const int* pad = (const int*)d_in[4];

  float* ctx = (float*)d_out;              // [8][2048][1024]
  float* W = ctx + (size_t)B_ * QL_ * D_;  // [8][2048][2048]

  const size_t MB = 1024 * 1024;
  // scratch layout (ws >= 96 MiB, confirmed in rounds 2-3):
  _Float16* VT = (_Float16*)d_ws;                     // [8][1024][2048] 32 MiB
  _Float16* Qh = (_Float16*)((char*)d_ws + 32 * MB);  // 32 MiB
  _Float16* Kh = (_Float16*)((char*)d_ws + 64 * MB);  // 32 MiB
  _Float16* Wh = Qh;                                  // 64 MiB, reused post-QK

  cvt_k<<<dim3(B_ * QL_ * D_ / 8 / 256), 256, 0, stream>>>(Q, Qh);
  cvt_k<<<dim3(B_ * KL_ * D_ / 8 / 256), 256, 0, stream>>>(K, Kh);
  vt_k<<<dim3(KL_ / 32, D_ / 32, B_), 256, 0, stream>>>(V, VT);
  fgemm_k<true><<<dim3(QL_ / 128, KL_ / 128, B_), 256, 0, stream>>>(
      Qh, Kh, W, mask, pad);
  softmax_k<<<dim3(B_ * QL_ / 4), 256, 0, stream>>>(W, Wh);
  fgemm_k<false><<<dim3(QL_ / 128, D_ / 128, B_), 256, 0, stream>>>(
      Wh, VT, ctx, nullptr, nullptr);
}

// Round 5
// 334.517 us; speedup vs baseline: 1.1364x; 1.1072x over previous
//
#include <hip/hip_runtime.h>
#include <hip/hip_fp16.h>

// Attention: ctx,W = softmax(Q K^T / 32 + mask, padmask) @ V
// B=8, QL=KL=2048, D=1024, fp32 I/O. fp16 MFMA internally (no fp32 MFMA on CDNA4).
#define B_ 8
#define QL_ 2048
#define KL_ 2048
#define D_ 1024

typedef _Float16 f16x8 __attribute__((ext_vector_type(8)));
typedef _Float16 f16x4 __attribute__((ext_vector_type(4)));
typedef float f32x4 __attribute__((ext_vector_type(4)));

// ---------------------------------------------------------------- async 16B
__device__ __forceinline__ void async16(const void* g, void* l) {
  __builtin_amdgcn_global_load_lds(
      (const __attribute__((address_space(1))) unsigned int*)g,
      (__attribute__((address_space(3))) unsigned int*)l, 16, 0, 0);
}

// ---------------------------------------------------------------- fp32->fp16
__global__ __launch_bounds__(256) void cvt_k(const float* __restrict__ X,
                                             _Float16* __restrict__ Xh) {
  const int i = blockIdx.x * 256 + threadIdx.x;  // one thread per 8 floats
  const float4* src = reinterpret_cast<const float4*>(X);
  float4 a = src[i * 2], b = src[i * 2 + 1];
  f16x8 h;
  h[0] = (_Float16)a.x; h[1] = (_Float16)a.y;
  h[2] = (_Float16)a.z; h[3] = (_Float16)a.w;
  h[4] = (_Float16)b.x; h[5] = (_Float16)b.y;
  h[6] = (_Float16)b.z; h[7] = (_Float16)b.w;
  reinterpret_cast<f16x8*>(Xh)[i] = h;
}

// ---------------------------------------------------------------- V transpose
__global__ __launch_bounds__(256) void vt_k(const float* __restrict__ V,
                                            _Float16* __restrict__ VT) {
  __shared__ float tile[32][33];
  const int k0 = blockIdx.x * 32, d0 = blockIdx.y * 32, b = blockIdx.z;
  const float* Vb = V + (size_t)b * KL_ * D_;
  _Float16* VTb = VT + (size_t)b * D_ * KL_;
  const int c = threadIdx.x & 31, r = threadIdx.x >> 5;
#pragma unroll
  for (int s = 0; s < 4; ++s)
    tile[r + s * 8][c] = Vb[(size_t)(k0 + r + s * 8) * D_ + d0 + c];
  __syncthreads();
#pragma unroll
  for (int s = 0; s < 4; ++s)
    VTb[(size_t)(d0 + r + s * 8) * KL_ + k0 + c] = (_Float16)tile[c][r + s * 8];
}

// ---------------------------------------------------------------- fast GEMM
// Verified 128x128/BK=32 tile (4 waves 2x2, 64x64/wave, 4x4 MFMA 16x16x32_f16,
// global_load_lds(16B) pre-swizzled source, 0 bank conflicts) + T4 counted-
// vmcnt ring-3 pipeline:
//   prologue: stage(0,s0) stage(1,s1)
//   iter t:   waitcnt vmcnt(4) lgkmcnt(0)   // oldest stage (tile t) landed;
//                                           // own ds_reads of t-1 executed
//             s_barrier                     // => ALL waves' t-stages landed
//             stage(t+2 -> slot of t-1)     // slot free: readers drained
//             ds_read(slot t) + 16 MFMA     // t+1,t+2 loads stay in flight
//   peeled last iter: vmcnt(0).
// Never vmcnt(0) in the main loop (T4); 48 KiB LDS -> 3 blocks/CU TLP.
// Epilogue is pure stores (mask/pad applied in softmax).
// SCORES=true : C[b][q][k] = raw QK^T   (Nc=2048, Kc=1024)
// SCORES=false: C[b][q][d] = W @ VT^T   (Nc=1024, Kc=2048)
template <bool SCORES>
__global__ __launch_bounds__(256, 3) void fgemm_k(
    const _Float16* __restrict__ Ah, const _Float16* __restrict__ Bh,
    float* __restrict__ Cg) {
  constexpr int Mc = 2048;
  constexpr int Nc = SCORES ? 2048 : 1024;
  constexpr int Kc = SCORES ? 1024 : 2048;
  constexpr int NIT = Kc / 32;
  constexpr int GX = Mc / 128, GY = Nc / 128;
  constexpr int CPX = B_ * GX * GY / 8;  // blocks per XCD chunk (exact)

  __shared__ alignas(16) _Float16 As[3][4096];  // 3 slots x 8 KiB
  __shared__ alignas(16) _Float16 Bs[3][4096];

  const int t = threadIdx.x;
  const int lane = t & 63;
  const int wid = t >> 6;
  const int wr = wid >> 1, wc = wid & 1;
  const int lo = lane & 15, hi = lane >> 4;

  // XCD-chunked swizzle (bijective: 8 | nwg): one batch per XCD ->
  // Qh/Kh (4 MiB/batch) ~ L2-resident.
  const int id = blockIdx.x;
  const int swz = (id & 7) * CPX + (id >> 3);
  const int b = swz / (GX * GY);
  const int rem = swz % (GX * GY);
  const int m0 = (rem / GY) * 128, n0 = (rem % GY) * 128;

  const _Float16* Ab = Ah + (size_t)b * Mc * Kc;
  const _Float16* Bb = Bh + (size_t)b * Nc * Kc;

  const int srow = t >> 2;  // staging row within a 64-row sweep
  const int dslot = t & 3;  // lane-linear LDS 16B slot within the row

  // precomputed per-thread global element offsets (pre-swizzled source chunk)
  size_t aoff[2], boff[2];
#pragma unroll
  for (int s = 0; s < 2; ++s) {
    const int row = s * 64 + srow;
    const int gs = dslot ^ ((row >> 1) & 3);
    aoff[s] = (size_t)(m0 + row) * Kc + gs * 8;
    boff[s] = (size_t)(n0 + row) * Kc + gs * 8;
  }

  auto stage = [&](int it, int slot) {
    const int kb = it * 32;
#pragma unroll
    for (int s = 0; s < 2; ++s) {
      async16(Ab + aoff[s] + kb, &As[slot][s * 2048 + wid * 512]);
      async16(Bb + boff[s] + kb, &Bs[slot][s * 2048 + wid * 512]);
    }
  };

  f32x4 acc[4][4];
#pragma unroll
  for (int m = 0; m < 4; ++m)
#pragma unroll
    for (int n = 0; n < 4; ++n)
#pragma unroll
      for (int i = 0; i < 4; ++i) acc[m][n][i] = 0.0f;

  // fragment LDS addresses (slot-invariant part)
  int raf[4], rbf_[4];
#pragma unroll
  for (int m = 0; m < 4; ++m) {
    const int r = wr * 64 + m * 16 + lo;
    raf[m] = r * 32 + (hi ^ ((r >> 1) & 3)) * 8;
  }
#pragma unroll
  for (int n = 0; n < 4; ++n) {
    const int r = wc * 64 + n * 16 + lo;
    rbf_[n] = r * 32 + (hi ^ ((r >> 1) & 3)) * 8;
  }

  auto compute = [&](int slot) {
    f16x8 af[4], bfr[4];
#pragma unroll
    for (int m = 0; m < 4; ++m)
      af[m] = *reinterpret_cast<const f16x8*>(&As[slot][raf[m]]);
#pragma unroll
    for (int n = 0; n < 4; ++n)
      bfr[n] = *reinterpret_cast<const f16x8*>(&Bs[slot][rbf_[n]]);
#pragma unroll
    for (int m = 0; m < 4; ++m)
#pragma unroll
      for (int n = 0; n < 4; ++n)
        acc[m][n] = __builtin_amdgcn_mfma_f32_16x16x32_f16(af[m], bfr[n],
                                                           acc[m][n], 0, 0, 0);
  };

  stage(0, 0);
  stage(1, 1);

  int slot = 0;
  for (int it = 0; it < NIT - 1; ++it) {
    // oldest stage (tile it) landed; own LDS reads of it-1 executed
    asm volatile("s_waitcnt vmcnt(4) lgkmcnt(0)" ::: "memory");
    __builtin_amdgcn_sched_barrier(0);
    __builtin_amdgcn_s_barrier();  // all waves' tile-it stages landed
    if (it + 2 < NIT) {
      int ps = slot + 2;
      if (ps >= 3) ps -= 3;
      stage(it + 2, ps);  // slot vacated by tile it-1
    }
    compute(slot);
    if (++slot == 3) slot = 0;
  }
  asm volatile("s_waitcnt vmcnt(0) lgkmcnt(0)" ::: "memory");
  __builtin_amdgcn_sched_barrier(0);
  __builtin_amdgcn_s_barrier();
  compute(slot);

  // Epilogue: pure stores. C layout: col = lane&15, row = (lane>>4)*4 + i.
  float* Cb = Cg + (size_t)b * Mc * Nc;
#pragma unroll
  for (int n = 0; n < 4; ++n) {
    const int col = n0 + wc * 64 + n * 16 + lo;
#pragma unroll
    for (int m = 0; m < 4; ++m) {
      const int r0 = m0 + wr * 64 + m * 16 + hi * 4;
#pragma unroll
      for (int i = 0; i < 4; ++i)
        Cb[(size_t)(r0 + i) * Nc + col] = acc[m][n][i];
    }
  }
}

// ---------------------------------------------------------------- row softmax
// One wave per row: load raw S, apply scale + attn_mask + pad fill (vectorized
// here instead of scalar in the GEMM epilogue), exact softmax, write W fp32 +
// Wh fp16. Masked -> -1e12 -> exp == 0 (matches jax); all-masked row ->
// uniform 1/2048 (matches jax).
__global__ __launch_bounds__(256) void softmax_k(float* __restrict__ W,
                                                 _Float16* __restrict__ Wh,
                                                 const float* __restrict__ mask,
                                                 const int* __restrict__ pad) {
  const int row = blockIdx.x * 4 + (threadIdx.x >> 6);
  const int lane = threadIdx.x & 63;
  const int b = row >> 11, q = row & 2047;
  float4* Wr = reinterpret_cast<float4*>(W + (size_t)row * KL_);
  const float4* Mr = reinterpret_cast<const float4*>(mask + (size_t)q * KL_);
  const int4* Pr = reinterpret_cast<const int4*>(pad + (size_t)b * KL_);
  const float inv_t = 0.03125f;  // 1/sqrt(1024)
  float4 v[8];
#pragma unroll
  for (int s = 0; s < 8; ++s) {
    float4 x = Wr[s * 64 + lane];
    float4 mk = Mr[s * 64 + lane];
    int4 p = Pr[s * 64 + lane];
    x.x = p.x ? -1e12f : x.x * inv_t + mk.x;
    x.y = p.y ? -1e12f : x.y * inv_t + mk.y;
    x.z = p.z ? -1e12f : x.z * inv_t + mk.z;
    x.w = p.w ? -1e12f : x.w * inv_t + mk.w;
    v[s] = x;
  }
  float mx = -3.402823466e38f;
#pragma unroll
  for (int s = 0; s < 8; ++s)
    mx = fmaxf(mx, fmaxf(fmaxf(v[s].x, v[s].y), fmaxf(v[s].z, v[s].w)));
#pragma unroll
  for (int off = 32; off > 0; off >>= 1) mx = fmaxf(mx, __shfl_xor(mx, off));
  float sum = 0.0f;
#pragma unroll
  for (int s = 0; s < 8; ++s) {
    v[s].x = __expf(v[s].x - mx);
    v[s].y = __expf(v[s].y - mx);
    v[s].z = __expf(v[s].z - mx);
    v[s].w = __expf(v[s].w - mx);
    sum += v[s].x + v[s].y + v[s].z + v[s].w;
  }
#pragma unroll
  for (int off = 32; off > 0; off >>= 1) sum += __shfl_xor(sum, off);
  const float inv = 1.0f / sum;
  f16x4* Whr = reinterpret_cast<f16x4*>(Wh + (size_t)row * KL_);
#pragma unroll
  for (int s = 0; s < 8; ++s) {
    float4 o;
    o.x = v[s].x * inv;
    o.y = v[s].y * inv;
    o.z = v[s].z * inv;
    o.w = v[s].w * inv;
    Wr[s * 64 + lane] = o;
    f16x4 h;
    h[0] = (_Float16)o.x;
    h[1] = (_Float16)o.y;
    h[2] = (_Float16)o.z;
    h[3] = (_Float16)o.w;
    Whr[s * 64 + lane] = h;
  }
}

// ---------------------------------------------------------------- launch
extern "C" void kernel_launch(void* const* d_in, const int* in_sizes, int n_in,
                              void* d_out, int out_size, void* d_ws,
                              size_t ws_size, hipStream_t stream) {
  const float* Q = (const float*)d_in[0];
  const float* K = (const float*)d_in[1];
  const float* V = (const float*)d_in[2];
  const float* mask = (const float*)d_in[3];
  const int* pad = (const int*)d_in[4];

  float* ctx = (float*)d_out;              // [8][2048][1024]
  float* W = ctx + (size_t)B_ * QL_ * D_;  // [8][2048][2048]

  const size_t MB = 1024 * 1024;
  // scratch layout (ws >= 96 MiB, confirmed in rounds 2-4):
  _Float16* VT = (_Float16*)d_ws;                     // [8][1024][2048] 32 MiB
  _Float16* Qh = (_Float16*)((char*)d_ws + 32 * MB);  // 32 MiB
  _Float16* Kh = (_Float16*)((char*)d_ws + 64 * MB);  // 32 MiB
  _Float16* Wh = Qh;                                  // 64 MiB, reused post-QK

  cvt_k<<<dim3(B_ * QL_ * D_ / 8 / 256), 256, 0, stream>>>(Q, Qh);
  cvt_k<<<dim3(B_ * KL_ * D_ / 8 / 256), 256, 0, stream>>>(K, Kh);
  vt_k<<<dim3(KL_ / 32, D_ / 32, B_), 256, 0, stream>>>(V, VT);
  fgemm_k<true><<<dim3(B_ * 16 * 16), 256, 0, stream>>>(Qh, Kh, W);
  softmax_k<<<dim3(B_ * QL_ / 4), 256, 0, stream>>>(W, Wh, mask, pad);
  fgemm_k<false><<<dim3(B_ * 16 * 8), 256, 0, stream>>>(Wh, VT, ctx);
}

// Round 6
// 291.249 us; speedup vs baseline: 1.3052x; 1.1486x over previous
//
#include <hip/hip_runtime.h>
#include <hip/hip_fp16.h>

// Attention: ctx,W = softmax(Q K^T / 32 + mask, padmask) @ V
// B=8, QL=KL=2048, D=1024, fp32 I/O. fp16 MFMA internally (no fp32 MFMA on CDNA4).
#define B_ 8
#define QL_ 2048
#define KL_ 2048
#define D_ 1024

typedef _Float16 f16x8 __attribute__((ext_vector_type(8)));
typedef _Float16 f16x4 __attribute__((ext_vector_type(4)));
typedef float f32x4 __attribute__((ext_vector_type(4)));

// ---------------------------------------------------------------- async 16B
__device__ __forceinline__ void async16(const void* g, void* l) {
  __builtin_amdgcn_global_load_lds(
      (const __attribute__((address_space(1))) unsigned int*)g,
      (__attribute__((address_space(3))) unsigned int*)l, 16, 0, 0);
}

// ---------------------------------------------------------------- fp32->fp16
__global__ __launch_bounds__(256) void cvt_k(const float* __restrict__ X,
                                             _Float16* __restrict__ Xh) {
  const int i = blockIdx.x * 256 + threadIdx.x;  // one thread per 8 floats
  const float4* src = reinterpret_cast<const float4*>(X);
  float4 a = src[i * 2], b = src[i * 2 + 1];
  f16x8 h;
  h[0] = (_Float16)a.x; h[1] = (_Float16)a.y;
  h[2] = (_Float16)a.z; h[3] = (_Float16)a.w;
  h[4] = (_Float16)b.x; h[5] = (_Float16)b.y;
  h[6] = (_Float16)b.z; h[7] = (_Float16)b.w;
  reinterpret_cast<f16x8*>(Xh)[i] = h;
}

// ---------------------------------------------------------------- V transpose
__global__ __launch_bounds__(256) void vt_k(const float* __restrict__ V,
                                            _Float16* __restrict__ VT) {
  __shared__ float tile[32][33];
  const int k0 = blockIdx.x * 32, d0 = blockIdx.y * 32, b = blockIdx.z;
  const float* Vb = V + (size_t)b * KL_ * D_;
  _Float16* VTb = VT + (size_t)b * D_ * KL_;
  const int c = threadIdx.x & 31, r = threadIdx.x >> 5;
#pragma unroll
  for (int s = 0; s < 4; ++s)
    tile[r + s * 8][c] = Vb[(size_t)(k0 + r + s * 8) * D_ + d0 + c];
  __syncthreads();
#pragma unroll
  for (int s = 0; s < 4; ++s)
    VTb[(size_t)(d0 + r + s * 8) * KL_ + k0 + c] = (_Float16)tile[c][r + s * 8];
}

// ---------------------------------------------------------------- fast GEMM
// Round-5 verified sync skeleton (counted-vmcnt ring pipeline, 0 bank
// conflicts) scaled to 256x256 tile, BK=32, 512 thr = 8 waves (2M x 4N),
// per-wave 128x64 out = 8x4 MFMA 16x16x32_f16 per K-step (32 MFMA/iter,
// 12 ds_read_b128/iter -> 42.7 FLOP per LDS byte).
// Ring-4 LDS (4 slots x (A 16K + B 16K) = 128 KiB dynamic), prefetch
// distance 3 tiles:
//   prologue: stage(0,s0) stage(1,s1) stage(2,s2)          [12 loads]
//   iter t:   waitcnt vmcnt(8) lgkmcnt(0)  // tile t landed (own 4 loads);
//                                          // own ds_reads of t-1 done
//             s_barrier                    // => ALL waves' t-stages landed
//             stage(t+3 -> slot of t-1)    // slot free: readers drained
//             ds_read(slot t) + 32 MFMA (setprio 1 around cluster)
//   peeled:   vmcnt(4), vmcnt(0) for the last two tiles.
// Never vmcnt(0) in the main loop (T4). Epilogue pure stores (mask/pad in
// softmax). SCORES=true: C=raw QK^T (Nc=2048,Kc=1024); else C=W@VT^T.
template <bool SCORES>
__global__ __launch_bounds__(512, 2) void fgemm_k(
    const _Float16* __restrict__ Ah, const _Float16* __restrict__ Bh,
    float* __restrict__ Cg) {
  constexpr int Mc = 2048;
  constexpr int Nc = SCORES ? 2048 : 1024;
  constexpr int Kc = SCORES ? 1024 : 2048;
  constexpr int NIT = Kc / 32;
  constexpr int GX = Mc / 256, GY = Nc / 256;
  constexpr int CPX = B_ * GX * GY / 8;  // blocks per XCD chunk (exact)

  extern __shared__ char lds[];  // 4 slots x 32 KiB (A 16K + B 16K each)

  const int t = threadIdx.x;
  const int lane = t & 63;
  const int wid = t >> 6;               // 0..7
  const int wr = wid >> 2, wc = wid & 3;
  const int lo = lane & 15, hi = lane >> 4;

  // XCD-chunked swizzle (bijective: 8 | nwg): scores = 1 batch per XCD.
  const int id = blockIdx.x;
  const int swz = (id & 7) * CPX + (id >> 3);
  const int b = swz / (GX * GY);
  const int rem = swz % (GX * GY);
  const int m0 = (rem / GY) * 256, n0 = (rem % GY) * 256;

  const _Float16* Ab = Ah + (size_t)b * Mc * Kc;
  const _Float16* Bb = Bh + (size_t)b * Nc * Kc;

  // ---- staging: per wave 2 instrs/matrix, each 1 KiB = 16 rows x 64 B.
  // LDS dest wave-uniform (+lane*16 by HW); global source pre-swizzled.
  size_t aoff[2], boff[2];
  int ldst[2];
#pragma unroll
  for (int j = 0; j < 2; ++j) {
    const int row = (wid * 2 + j) * 16 + (lane >> 2);  // 0..255
    const int ch = (lane & 3) ^ ((row >> 1) & 3);      // source 16B chunk
    aoff[j] = (size_t)(m0 + row) * Kc + ch * 8;
    boff[j] = (size_t)(n0 + row) * Kc + ch * 8;
    ldst[j] = (wid * 2 + j) * 1024;  // wave-uniform byte offset
  }

  auto stage = [&](int it, int slot) {
    char* base = lds + slot * 32768;
    const int kb = it * 32;
#pragma unroll
    for (int j = 0; j < 2; ++j) {
      async16(Ab + aoff[j] + kb, base + ldst[j]);
      async16(Bb + boff[j] + kb, base + 16384 + ldst[j]);
    }
  };

  f32x4 acc[8][4];
#pragma unroll
  for (int m = 0; m < 8; ++m)
#pragma unroll
    for (int n = 0; n < 4; ++n)
#pragma unroll
      for (int i = 0; i < 4; ++i) acc[m][n][i] = 0.0f;

  // fragment LDS byte offsets (row*64 + swizzled-chunk*16)
  int raf[8], rbf_[4];
#pragma unroll
  for (int m = 0; m < 8; ++m) {
    const int r = wr * 128 + m * 16 + lo;
    raf[m] = r * 64 + ((hi ^ ((r >> 1) & 3)) << 4);
  }
#pragma unroll
  for (int n = 0; n < 4; ++n) {
    const int r = wc * 64 + n * 16 + lo;
    rbf_[n] = r * 64 + ((hi ^ ((r >> 1) & 3)) << 4);
  }

  auto compute = [&](int slot) {
    const char* Ac = lds + slot * 32768;
    const char* Bc = Ac + 16384;
    f16x8 af[8], bfr[4];
#pragma unroll
    for (int m = 0; m < 8; ++m)
      af[m] = *reinterpret_cast<const f16x8*>(Ac + raf[m]);
#pragma unroll
    for (int n = 0; n < 4; ++n)
      bfr[n] = *reinterpret_cast<const f16x8*>(Bc + rbf_[n]);
    __builtin_amdgcn_s_setprio(1);
#pragma unroll
    for (int m = 0; m < 8; ++m)
#pragma unroll
      for (int n = 0; n < 4; ++n)
        acc[m][n] = __builtin_amdgcn_mfma_f32_16x16x32_f16(af[m], bfr[n],
                                                           acc[m][n], 0, 0, 0);
    __builtin_amdgcn_s_setprio(0);
  };

  stage(0, 0);
  stage(1, 1);
  stage(2, 2);

  for (int it = 0; it < NIT - 2; ++it) {
    asm volatile("s_waitcnt vmcnt(8) lgkmcnt(0)" ::: "memory");
    __builtin_amdgcn_sched_barrier(0);
    __builtin_amdgcn_s_barrier();
    if (it + 3 < NIT) stage(it + 3, (it + 3) & 3);
    compute(it & 3);
  }
  asm volatile("s_waitcnt vmcnt(4) lgkmcnt(0)" ::: "memory");
  __builtin_amdgcn_sched_barrier(0);
  __builtin_amdgcn_s_barrier();
  compute((NIT - 2) & 3);
  asm volatile("s_waitcnt vmcnt(0) lgkmcnt(0)" ::: "memory");
  __builtin_amdgcn_sched_barrier(0);
  __builtin_amdgcn_s_barrier();
  compute((NIT - 1) & 3);

  // Epilogue: pure stores. C layout: col = lane&15, row = (lane>>4)*4 + i.
  float* Cb = Cg + (size_t)b * Mc * Nc;
#pragma unroll
  for (int n = 0; n < 4; ++n) {
    const int col = n0 + wc * 64 + n * 16 + lo;
#pragma unroll
    for (int m = 0; m < 8; ++m) {
      const int r0 = m0 + wr * 128 + m * 16 + hi * 4;
#pragma unroll
      for (int i = 0; i < 4; ++i)
        Cb[(size_t)(r0 + i) * Nc + col] = acc[m][n][i];
    }
  }
}

// ---------------------------------------------------------------- row softmax
// One wave per row: apply scale + attn_mask + pad fill (vectorized), exact
// softmax, write W fp32 + Wh fp16. Masked -> -1e12 -> exp == 0 (matches jax);
// all-masked row -> uniform 1/2048 (matches jax).
__global__ __launch_bounds__(256) void softmax_k(float* __restrict__ W,
                                                 _Float16* __restrict__ Wh,
                                                 const float* __restrict__ mask,
                                                 const int* __restrict__ pad) {
  const int row = blockIdx.x * 4 + (threadIdx.x >> 6);
  const int lane = threadIdx.x & 63;
  const int b = row >> 11, q = row & 2047;
  float4* Wr = reinterpret_cast<float4*>(W + (size_t)row * KL_);
  const float4* Mr = reinterpret_cast<const float4*>(mask + (size_t)q * KL_);
  const int4* Pr = reinterpret_cast<const int4*>(pad + (size_t)b * KL_);
  const float inv_t = 0.03125f;  // 1/sqrt(1024)
  float4 v[8];
#pragma unroll
  for (int s = 0; s < 8; ++s) {
    float4 x = Wr[s * 64 + lane];
    float4 mk = Mr[s * 64 + lane];
    int4 p = Pr[s * 64 + lane];
    x.x = p.x ? -1e12f : x.x * inv_t + mk.x;
    x.y = p.y ? -1e12f : x.y * inv_t + mk.y;
    x.z = p.z ? -1e12f : x.z * inv_t + mk.z;
    x.w = p.w ? -1e12f : x.w * inv_t + mk.w;
    v[s] = x;
  }
  float mx = -3.402823466e38f;
#pragma unroll
  for (int s = 0; s < 8; ++s)
    mx = fmaxf(mx, fmaxf(fmaxf(v[s].x, v[s].y), fmaxf(v[s].z, v[s].w)));
#pragma unroll
  for (int off = 32; off > 0; off >>= 1) mx = fmaxf(mx, __shfl_xor(mx, off));
  float sum = 0.0f;
#pragma unroll
  for (int s = 0; s < 8; ++s) {
    v[s].x = __expf(v[s].x - mx);
    v[s].y = __expf(v[s].y - mx);
    v[s].z = __expf(v[s].z - mx);
    v[s].w = __expf(v[s].w - mx);
    sum += v[s].x + v[s].y + v[s].z + v[s].w;
  }
#pragma unroll
  for (int off = 32; off > 0; off >>= 1) sum += __shfl_xor(sum, off);
  const float inv = 1.0f / sum;
  f16x4* Whr = reinterpret_cast<f16x4*>(Wh + (size_t)row * KL_);
#pragma unroll
  for (int s = 0; s < 8; ++s) {
    float4 o;
    o.x = v[s].x * inv;
    o.y = v[s].y * inv;
    o.z = v[s].z * inv;
    o.w = v[s].w * inv;
    Wr[s * 64 + lane] = o;
    f16x4 h;
    h[0] = (_Float16)o.x;
    h[1] = (_Float16)o.y;
    h[2] = (_Float16)o.z;
    h[3] = (_Float16)o.w;
    Whr[s * 64 + lane] = h;
  }
}

// ---------------------------------------------------------------- launch
extern "C" void kernel_launch(void* const* d_in, const int* in_sizes, int n_in,
                              void* d_out, int out_size, void* d_ws,
                              size_t ws_size, hipStream_t stream) {
  const float* Q = (const float*)d_in[0];
  const float* K = (const float*)d_in[1];
  const float* V = (const float*)d_in[2];
  const float* mask = (const float*)d_in[3];
  const int* pad = (const int*)d_in[4];

  float* ctx = (float*)d_out;              // [8][2048][1024]
  float* W = ctx + (size_t)B_ * QL_ * D_;  // [8][2048][2048]

  const size_t MB = 1024 * 1024;
  // scratch layout (ws >= 96 MiB, confirmed in rounds 2-5):
  _Float16* VT = (_Float16*)d_ws;                     // [8][1024][2048] 32 MiB
  _Float16* Qh = (_Float16*)((char*)d_ws + 32 * MB);  // 32 MiB
  _Float16* Kh = (_Float16*)((char*)d_ws + 64 * MB);  // 32 MiB
  _Float16* Wh = Qh;                                  // 64 MiB, reused post-QK

  // opt-in to 128 KiB dynamic LDS (idempotent, non-stream API)
  (void)hipFuncSetAttribute((const void*)fgemm_k<true>,
                            hipFuncAttributeMaxDynamicSharedMemorySize, 131072);
  (void)hipFuncSetAttribute((const void*)fgemm_k<false>,
                            hipFuncAttributeMaxDynamicSharedMemorySize, 131072);

  cvt_k<<<dim3(B_ * QL_ * D_ / 8 / 256), 256, 0, stream>>>(Q, Qh);
  cvt_k<<<dim3(B_ * KL_ * D_ / 8 / 256), 256, 0, stream>>>(K, Kh);
  vt_k<<<dim3(KL_ / 32, D_ / 32, B_), 256, 0, stream>>>(V, VT);
  fgemm_k<true><<<dim3(B_ * 8 * 8), 512, 131072, stream>>>(Qh, Kh, W);
  softmax_k<<<dim3(B_ * QL_ / 4), 256, 0, stream>>>(W, Wh, mask, pad);
  fgemm_k<false><<<dim3(B_ * 8 * 4), 512, 131072, stream>>>(Wh, VT, ctx);
}

// Round 7
// 284.424 us; speedup vs baseline: 1.3365x; 1.0240x over previous
//
#include <hip/hip_runtime.h>
#include <hip/hip_fp16.h>

// Attention: ctx,W = softmax(Q K^T / 32 + mask, padmask) @ V
// B=8, QL=KL=2048, D=1024, fp32 I/O. fp16 MFMA internally (no fp32 MFMA on CDNA4).
#define B_ 8
#define QL_ 2048
#define KL_ 2048
#define D_ 1024

typedef _Float16 f16x8 __attribute__((ext_vector_type(8)));
typedef _Float16 f16x4 __attribute__((ext_vector_type(4)));
typedef float f32x4 __attribute__((ext_vector_type(4)));

// ---------------------------------------------------------------- async 16B
__device__ __forceinline__ void async16(const void* g, void* l) {
  __builtin_amdgcn_global_load_lds(
      (const __attribute__((address_space(1))) unsigned int*)g,
      (__attribute__((address_space(3))) unsigned int*)l, 16, 0, 0);
}

// ---------------------------------------------------------------- fp32->fp16
// scale folded in: Qh = (half)(Q/32) so the scores GEMM emits S' = S/sqrt(D)
// directly (also improves S' fp16 range: |S'|<~6).
__global__ __launch_bounds__(256) void cvt_k(const float* __restrict__ X,
                                             _Float16* __restrict__ Xh,
                                             float scale) {
  const int i = blockIdx.x * 256 + threadIdx.x;  // one thread per 8 floats
  const float4* src = reinterpret_cast<const float4*>(X);
  float4 a = src[i * 2], b = src[i * 2 + 1];
  f16x8 h;
  h[0] = (_Float16)(a.x * scale); h[1] = (_Float16)(a.y * scale);
  h[2] = (_Float16)(a.z * scale); h[3] = (_Float16)(a.w * scale);
  h[4] = (_Float16)(b.x * scale); h[5] = (_Float16)(b.y * scale);
  h[6] = (_Float16)(b.z * scale); h[7] = (_Float16)(b.w * scale);
  reinterpret_cast<f16x8*>(Xh)[i] = h;
}

// ---------------------------------------------------------------- V transpose
__global__ __launch_bounds__(256) void vt_k(const float* __restrict__ V,
                                            _Float16* __restrict__ VT) {
  __shared__ float tile[32][33];
  const int k0 = blockIdx.x * 32, d0 = blockIdx.y * 32, b = blockIdx.z;
  const float* Vb = V + (size_t)b * KL_ * D_;
  _Float16* VTb = VT + (size_t)b * D_ * KL_;
  const int c = threadIdx.x & 31, r = threadIdx.x >> 5;
#pragma unroll
  for (int s = 0; s < 4; ++s)
    tile[r + s * 8][c] = Vb[(size_t)(k0 + r + s * 8) * D_ + d0 + c];
  __syncthreads();
#pragma unroll
  for (int s = 0; s < 4; ++s)
    VTb[(size_t)(d0 + r + s * 8) * KL_ + k0 + c] = (_Float16)tile[c][r + s * 8];
}

// ---------------------------------------------------------------- fast GEMM
// Verified counted-vmcnt ring skeleton (rounds 5/6, 0 bank conflicts),
// 256x256 tile, BK=32, 512 thr = 8 waves (2M x 4N), per-wave 128x64 out =
// 32 MFMA 16x16x32_f16 per K-step, 12 ds_read_b128/iter.
// Ring-5 LDS (5 slots x 32 KiB = 160 KiB dynamic), prefetch distance 4:
//   prologue: stage tiles 0..3 -> slots 0..3                 [16 loads]
//   iter t:   waitcnt vmcnt(12) lgkmcnt(0) // tile t landed (own 4 loads);
//                                          // own ds_reads of t-1 done
//             s_barrier                    // => ALL waves' t-stages landed
//             stage(t+4 -> slot of t-1)    // slot free: readers drained
//             ds_read(slot t) + 32 MFMA (setprio 1 around cluster)
//   peeled:   vmcnt(8), vmcnt(4), vmcnt(0) for the last three tiles.
// Never vmcnt(0) in the main loop (T4). Epilogue pure stores (mask/pad in
// softmax). SCORES=true: S' = Qh.Kh^T stored fp16 (Nc=2048, Kc=1024);
// SCORES=false: ctx = W @ VT^T stored fp32 (Nc=1024, Kc=2048).
template <bool SCORES>
__global__ __launch_bounds__(512, 2) void fgemm_k(
    const _Float16* __restrict__ Ah, const _Float16* __restrict__ Bh,
    float* __restrict__ Cf, _Float16* __restrict__ Ch) {
  constexpr int Mc = 2048;
  constexpr int Nc = SCORES ? 2048 : 1024;
  constexpr int Kc = SCORES ? 1024 : 2048;
  constexpr int NIT = Kc / 32;
  constexpr int GX = Mc / 256, GY = Nc / 256;
  constexpr int CPX = B_ * GX * GY / 8;  // blocks per XCD chunk (exact)

  extern __shared__ char lds[];  // 5 slots x 32 KiB (A 16K + B 16K each)

  const int t = threadIdx.x;
  const int lane = t & 63;
  const int wid = t >> 6;               // 0..7
  const int wr = wid >> 2, wc = wid & 3;
  const int lo = lane & 15, hi = lane >> 4;

  // XCD-chunked swizzle (bijective: 8 | nwg): scores = 1 batch per XCD.
  const int id = blockIdx.x;
  const int swz = (id & 7) * CPX + (id >> 3);
  const int b = swz / (GX * GY);
  const int rem = swz % (GX * GY);
  const int m0 = (rem / GY) * 256, n0 = (rem % GY) * 256;

  const _Float16* Ab = Ah + (size_t)b * Mc * Kc;
  const _Float16* Bb = Bh + (size_t)b * Nc * Kc;

  // ---- staging: per wave 2 instrs/matrix, each 1 KiB = 16 rows x 64 B.
  // LDS dest wave-uniform (+lane*16 by HW); global source pre-swizzled.
  size_t aoff[2], boff[2];
  int ldst[2];
#pragma unroll
  for (int j = 0; j < 2; ++j) {
    const int row = (wid * 2 + j) * 16 + (lane >> 2);  // 0..255
    const int ch = (lane & 3) ^ ((row >> 1) & 3);      // source 16B chunk
    aoff[j] = (size_t)(m0 + row) * Kc + ch * 8;
    boff[j] = (size_t)(n0 + row) * Kc + ch * 8;
    ldst[j] = (wid * 2 + j) * 1024;  // wave-uniform byte offset
  }

  auto stage = [&](int it, int slot) {
    char* base = lds + slot * 32768;
    const int kb = it * 32;
#pragma unroll
    for (int j = 0; j < 2; ++j) {
      async16(Ab + aoff[j] + kb, base + ldst[j]);
      async16(Bb + boff[j] + kb, base + 16384 + ldst[j]);
    }
  };

  f32x4 acc[8][4];
#pragma unroll
  for (int m = 0; m < 8; ++m)
#pragma unroll
    for (int n = 0; n < 4; ++n)
#pragma unroll
      for (int i = 0; i < 4; ++i) acc[m][n][i] = 0.0f;

  // fragment LDS byte offsets (row*64 + swizzled-chunk*16)
  int raf[8], rbf_[4];
#pragma unroll
  for (int m = 0; m < 8; ++m) {
    const int r = wr * 128 + m * 16 + lo;
    raf[m] = r * 64 + ((hi ^ ((r >> 1) & 3)) << 4);
  }
#pragma unroll
  for (int n = 0; n < 4; ++n) {
    const int r = wc * 64 + n * 16 + lo;
    rbf_[n] = r * 64 + ((hi ^ ((r >> 1) & 3)) << 4);
  }

  auto compute = [&](int slot) {
    const char* Ac = lds + slot * 32768;
    const char* Bc = Ac + 16384;
    f16x8 af[8], bfr[4];
#pragma unroll
    for (int m = 0; m < 8; ++m)
      af[m] = *reinterpret_cast<const f16x8*>(Ac + raf[m]);
#pragma unroll
    for (int n = 0; n < 4; ++n)
      bfr[n] = *reinterpret_cast<const f16x8*>(Bc + rbf_[n]);
    __builtin_amdgcn_s_setprio(1);
#pragma unroll
    for (int m = 0; m < 8; ++m)
#pragma unroll
      for (int n = 0; n < 4; ++n)
        acc[m][n] = __builtin_amdgcn_mfma_f32_16x16x32_f16(af[m], bfr[n],
                                                           acc[m][n], 0, 0, 0);
    __builtin_amdgcn_s_setprio(0);
  };

  stage(0, 0);
  stage(1, 1);
  stage(2, 2);
  stage(3, 3);

  int cs = 0, ss = 4;  // compute slot, stage slot (ring of 5)
  for (int it = 0; it < NIT - 3; ++it) {
    asm volatile("s_waitcnt vmcnt(12) lgkmcnt(0)" ::: "memory");
    __builtin_amdgcn_sched_barrier(0);
    __builtin_amdgcn_s_barrier();
    if (it + 4 < NIT) {
      stage(it + 4, ss);
      if (++ss == 5) ss = 0;
    }
    compute(cs);
    if (++cs == 5) cs = 0;
  }
  asm volatile("s_waitcnt vmcnt(8) lgkmcnt(0)" ::: "memory");
  __builtin_amdgcn_sched_barrier(0);
  __builtin_amdgcn_s_barrier();
  compute(cs);
  if (++cs == 5) cs = 0;
  asm volatile("s_waitcnt vmcnt(4) lgkmcnt(0)" ::: "memory");
  __builtin_amdgcn_sched_barrier(0);
  __builtin_amdgcn_s_barrier();
  compute(cs);
  if (++cs == 5) cs = 0;
  asm volatile("s_waitcnt vmcnt(0) lgkmcnt(0)" ::: "memory");
  __builtin_amdgcn_sched_barrier(0);
  __builtin_amdgcn_s_barrier();
  compute(cs);

  // Epilogue: pure stores. C layout: col = lane&15, row = (lane>>4)*4 + i.
  if constexpr (SCORES) {
    _Float16* Cb = Ch + (size_t)b * Mc * Nc;  // S' fp16 into ctx region
#pragma unroll
    for (int n = 0; n < 4; ++n) {
      const int col = n0 + wc * 64 + n * 16 + lo;
#pragma unroll
      for (int m = 0; m < 8; ++m) {
        const int r0 = m0 + wr * 128 + m * 16 + hi * 4;
#pragma unroll
        for (int i = 0; i < 4; ++i)
          Cb[(size_t)(r0 + i) * Nc + col] = (_Float16)acc[m][n][i];
      }
    }
  } else {
    float* Cb = Cf + (size_t)b * Mc * Nc;
#pragma unroll
    for (int n = 0; n < 4; ++n) {
      const int col = n0 + wc * 64 + n * 16 + lo;
#pragma unroll
      for (int m = 0; m < 8; ++m) {
        const int r0 = m0 + wr * 128 + m * 16 + hi * 4;
#pragma unroll
        for (int i = 0; i < 4; ++i)
          Cb[(size_t)(r0 + i) * Nc + col] = acc[m][n][i];
      }
    }
  }
}

// ---------------------------------------------------------------- row softmax
// One wave per row: read S' fp16 (already scaled by 1/sqrt(D)), add attn_mask,
// pad fill -1e12, exact softmax, write W fp32 + Wh fp16. Masked -> exp == 0
// (matches jax); all-masked row -> uniform 1/2048 (matches jax).
__global__ __launch_bounds__(256) void softmax_k(
    const _Float16* __restrict__ Sh, float* __restrict__ W,
    _Float16* __restrict__ Wh, const float* __restrict__ mask,
    const int* __restrict__ pad) {
  const int row = blockIdx.x * 4 + (threadIdx.x >> 6);
  const int lane = threadIdx.x & 63;
  const int b = row >> 11, q = row & 2047;
  const f16x4* Sr = reinterpret_cast<const f16x4*>(Sh + (size_t)row * KL_);
  float4* Wr = reinterpret_cast<float4*>(W + (size_t)row * KL_);
  const float4* Mr = reinterpret_cast<const float4*>(mask + (size_t)q * KL_);
  const int4* Pr = reinterpret_cast<const int4*>(pad + (size_t)b * KL_);
  float4 v[8];
#pragma unroll
  for (int s = 0; s < 8; ++s) {
    f16x4 sv = Sr[s * 64 + lane];
    float4 mk = Mr[s * 64 + lane];
    int4 p = Pr[s * 64 + lane];
    float4 x;
    x.x = p.x ? -1e12f : (float)sv[0] + mk.x;
    x.y = p.y ? -1e12f : (float)sv[1] + mk.y;
    x.z = p.z ? -1e12f : (float)sv[2] + mk.z;
    x.w = p.w ? -1e12f : (float)sv[3] + mk.w;
    v[s] = x;
  }
  float mx = -3.402823466e38f;
#pragma unroll
  for (int s = 0; s < 8; ++s)
    mx = fmaxf(mx, fmaxf(fmaxf(v[s].x, v[s].y), fmaxf(v[s].z, v[s].w)));
#pragma unroll
  for (int off = 32; off > 0; off >>= 1) mx = fmaxf(mx, __shfl_xor(mx, off));
  float sum = 0.0f;
#pragma unroll
  for (int s = 0; s < 8; ++s) {
    v[s].x = __expf(v[s].x - mx);
    v[s].y = __expf(v[s].y - mx);
    v[s].z = __expf(v[s].z - mx);
    v[s].w = __expf(v[s].w - mx);
    sum += v[s].x + v[s].y + v[s].z + v[s].w;
  }
#pragma unroll
  for (int off = 32; off > 0; off >>= 1) sum += __shfl_xor(sum, off);
  const float inv = 1.0f / sum;
  f16x4* Whr = reinterpret_cast<f16x4*>(Wh + (size_t)row * KL_);
#pragma unroll
  for (int s = 0; s < 8; ++s) {
    float4 o;
    o.x = v[s].x * inv;
    o.y = v[s].y * inv;
    o.z = v[s].z * inv;
    o.w = v[s].w * inv;
    Wr[s * 64 + lane] = o;
    f16x4 h;
    h[0] = (_Float16)o.x;
    h[1] = (_Float16)o.y;
    h[2] = (_Float16)o.z;
    h[3] = (_Float16)o.w;
    Whr[s * 64 + lane] = h;
  }
}

// ---------------------------------------------------------------- launch
extern "C" void kernel_launch(void* const* d_in, const int* in_sizes, int n_in,
                              void* d_out, int out_size, void* d_ws,
                              size_t ws_size, hipStream_t stream) {
  const float* Q = (const float*)d_in[0];
  const float* K = (const float*)d_in[1];
  const float* V = (const float*)d_in[2];
  const float* mask = (const float*)d_in[3];
  const int* pad = (const int*)d_in[4];

  float* ctx = (float*)d_out;              // [8][2048][1024] fp32 (final)
  float* W = ctx + (size_t)B_ * QL_ * D_;  // [8][2048][2048] fp32 (final)
  // S' fp16 scratch: EXACTLY the ctx region (64 MiB). Dead until PV runs;
  // strict stream order (scores -> softmax -> PV) makes the reuse safe.
  _Float16* Sh = (_Float16*)d_out;

  const size_t MB = 1024 * 1024;
  // d_ws layout (>= 96 MiB, confirmed rounds 2-6):
  _Float16* VT = (_Float16*)d_ws;                     // [8][1024][2048] 32 MiB
  _Float16* Qh = (_Float16*)((char*)d_ws + 32 * MB);  // 32 MiB
  _Float16* Kh = (_Float16*)((char*)d_ws + 64 * MB);  // 32 MiB
  _Float16* Wh = Qh;                                  // 64 MiB, reused post-QK

  // opt-in to 160 KiB dynamic LDS (idempotent, non-stream API)
  (void)hipFuncSetAttribute((const void*)fgemm_k<true>,
                            hipFuncAttributeMaxDynamicSharedMemorySize, 163840);
  (void)hipFuncSetAttribute((const void*)fgemm_k<false>,
                            hipFuncAttributeMaxDynamicSharedMemorySize, 163840);

  cvt_k<<<dim3(B_ * QL_ * D_ / 8 / 256), 256, 0, stream>>>(Q, Qh, 0.03125f);
  cvt_k<<<dim3(B_ * KL_ * D_ / 8 / 256), 256, 0, stream>>>(K, Kh, 1.0f);
  vt_k<<<dim3(KL_ / 32, D_ / 32, B_), 256, 0, stream>>>(V, VT);
  fgemm_k<true><<<dim3(B_ * 8 * 8), 512, 163840, stream>>>(Qh, Kh, nullptr, Sh);
  softmax_k<<<dim3(B_ * QL_ / 4), 256, 0, stream>>>(Sh, W, Wh, mask, pad);
  fgemm_k<false><<<dim3(B_ * 8 * 4), 512, 163840, stream>>>(Wh, VT, ctx,
                                                            nullptr);
}